// Round 1
// baseline (576.884 us; speedup 1.0000x reference)
//
#include <hip/hip_runtime.h>

// Edge MLP: out = relu(concat(x[src], x[tgt], edge_attr) @ W1 + b1) @ W2 + b2
// E=640000, NODE=128, EA=64, IN=320, OUT=128. fp32 in/out, bf16 MFMA compute.
//
// Strategy:
//  - prep kernel: W1/W2 fp32 -> bf16 in MFMA B-fragment-linear layout in d_ws
//    (frag = 64 lanes x 16B contiguous; B[n=lane&31][k=ks*16+(lane>>5)*8+j])
//  - main kernel: BM=256 edges/block, 512 thr (8 waves), each wave a 64x64 tile
//    (2x2 of v_mfma_f32_32x32x16_bf16). A staged in 3 phases into one 64KB LDS
//    buffer in A-fragment-linear order; h (relu) round-trips through same
//    buffer; W2 reuses W1's LDS region after GEMM1. LDS total 147KB -> 1 blk/CU.

typedef __bf16 bf16;
typedef __attribute__((ext_vector_type(8)))  __bf16 bf16x8;
typedef __attribute__((ext_vector_type(4)))  __bf16 bf16x4;
typedef __attribute__((ext_vector_type(16))) float  f32x16;

#define N_EDGES 640000
#define BM      256
#define NTHR    512

// ---------------- weight prep: fp32 row-major -> bf16 fragment-linear ----------
// W1 frags: [nt(4)][ks(20)][lane(64)][j(8)]  element = W1[k*128+n],
//   n = nt*32 + (lane&31), k = ks*16 + (lane>>5)*8 + j     (40960 elems)
// W2 frags: [nt(4)][ks(8)][lane(64)][j(8)]   element = W2[k*128+n]  (16384 elems)
__global__ void prep_weights(const float* __restrict__ W1, const float* __restrict__ W2,
                             bf16* __restrict__ w1f, bf16* __restrict__ w2f) {
    int i = blockIdx.x * 256 + threadIdx.x;
    if (i < 40960) {
        int j = i & 7, l = (i >> 3) & 63, q = i >> 9;   // q in [0,80)
        int ks = q % 20, nt = q / 20;
        int n = nt * 32 + (l & 31);
        int k = ks * 16 + ((l >> 5) << 3) + j;
        w1f[i] = (bf16)W1[k * 128 + n];
    } else if (i < 40960 + 16384) {
        int i2 = i - 40960;
        int j = i2 & 7, l = (i2 >> 3) & 63, q = i2 >> 9; // q in [0,32)
        int ks = q & 7, nt = q >> 3;
        int n = nt * 32 + (l & 31);
        int k = ks * 16 + ((l >> 5) << 3) + j;
        w2f[i2] = (bf16)W2[k * 128 + n];
    }
}

// h write: C-layout (col=lane&31, row=(r&3)+8*(r>>2)+4*(lane>>5)) -> A-frag-linear LDS
__device__ __forceinline__ void write_h(const f32x16& a, int mt, int nt, int ln, int rowq,
                                        bf16* sA, const float* sB1) {
    const int n    = nt * 32 + ln;
    const float bi = sB1[n];
    const int base = ((mt * 8 + (n >> 4)) * 64 + ((n >> 3) & 1) * 32) * 8 + (n & 7);
#pragma unroll
    for (int r = 0; r < 16; ++r) {
        const int ml = (r & 3) + ((r >> 2) << 3) + rowq;
        float v = a[r] + bi;
        sA[base + ml * 8] = (bf16)fmaxf(v, 0.f);
    }
}

__device__ __forceinline__ void write_out(const f32x16& a, int mt, int nt, int ln, int rowq,
                                          int ebase, const float* sB2, float* out) {
    const int n    = nt * 32 + ln;
    const float bi = sB2[n];
#pragma unroll
    for (int r = 0; r < 16; ++r) {
        const int ml = (r & 3) + ((r >> 2) << 3) + rowq;
        const size_t off = (size_t)(ebase + mt * 32 + ml) * 128 + n;
        __builtin_nontemporal_store(a[r] + bi, &out[off]);
    }
}

#define G1_STEP(KL, KS) {                                                          \
    bf16x8 a0  = *(const bf16x8*)&sA[((mt0 * 8 + (KL)) * 64 + lane) * 8];          \
    bf16x8 a1  = *(const bf16x8*)&sA[(((mt0 + 1) * 8 + (KL)) * 64 + lane) * 8];    \
    bf16x8 bb0 = *(const bf16x8*)&sW[((nt0 * 20 + (KS)) * 64 + lane) * 8];         \
    bf16x8 bb1 = *(const bf16x8*)&sW[(((nt0 + 1) * 20 + (KS)) * 64 + lane) * 8];   \
    acc00 = __builtin_amdgcn_mfma_f32_32x32x16_bf16(a0, bb0, acc00, 0, 0, 0);      \
    acc01 = __builtin_amdgcn_mfma_f32_32x32x16_bf16(a0, bb1, acc01, 0, 0, 0);      \
    acc10 = __builtin_amdgcn_mfma_f32_32x32x16_bf16(a1, bb0, acc10, 0, 0, 0);      \
    acc11 = __builtin_amdgcn_mfma_f32_32x32x16_bf16(a1, bb1, acc11, 0, 0, 0); }

#define G2_STEP(KS) {                                                              \
    bf16x8 a0  = *(const bf16x8*)&sA[((mt0 * 8 + (KS)) * 64 + lane) * 8];          \
    bf16x8 a1  = *(const bf16x8*)&sA[(((mt0 + 1) * 8 + (KS)) * 64 + lane) * 8];    \
    bf16x8 bb0 = *(const bf16x8*)&sW[((nt0 * 8 + (KS)) * 64 + lane) * 8];          \
    bf16x8 bb1 = *(const bf16x8*)&sW[(((nt0 + 1) * 8 + (KS)) * 64 + lane) * 8];    \
    acc00 = __builtin_amdgcn_mfma_f32_32x32x16_bf16(a0, bb0, acc00, 0, 0, 0);      \
    acc01 = __builtin_amdgcn_mfma_f32_32x32x16_bf16(a0, bb1, acc01, 0, 0, 0);      \
    acc10 = __builtin_amdgcn_mfma_f32_32x32x16_bf16(a1, bb0, acc10, 0, 0, 0);      \
    acc11 = __builtin_amdgcn_mfma_f32_32x32x16_bf16(a1, bb1, acc11, 0, 0, 0); }

__global__ __launch_bounds__(NTHR, 2) void edge_mlp(
    const float* __restrict__ x, const int* __restrict__ eidx,
    const float* __restrict__ eattr, const bf16* __restrict__ w1f,
    const float* __restrict__ b1, const bf16* __restrict__ w2f,
    const float* __restrict__ b2, float* __restrict__ out)
{
    extern __shared__ char smem[];
    bf16*  sW   = (bf16*)smem;                      // 40960 bf16 = 81920 B (W1; W2 reuses)
    bf16*  sA   = (bf16*)(smem + 81920);            // 32768 bf16 = 65536 B (A chunk / h)
    int*   sSrc = (int*)(smem + 81920 + 65536);     // 256
    int*   sTgt = sSrc + 256;                       // 256
    float* sB1  = (float*)(sTgt + 256);             // 128
    float* sB2  = sB1 + 128;                        // 128   total 150528 B

    const int tid   = threadIdx.x;
    const int wave  = tid >> 6;
    const int lane  = tid & 63;
    const int ebase = blockIdx.x * BM;

    // ---- stage indices + biases + W1 fragments (no barrier needed until use)
    if (tid < BM) sSrc[tid] = eidx[ebase + tid];
    else          sTgt[tid - BM] = eidx[N_EDGES + ebase + (tid - BM)];
    if (tid < 128)        sB1[tid] = b1[tid];
    if (tid >= NTHR - 128) sB2[tid - (NTHR - 128)] = b2[tid - (NTHR - 128)];
    {
        const uint4* s4 = (const uint4*)w1f;
        uint4*       d4 = (uint4*)sW;
#pragma unroll
        for (int i = 0; i < 10; ++i) d4[i * NTHR + tid] = s4[i * NTHR + tid];
    }

    const int mt0 = (wave >> 1) * 2;   // wave -> 2x2 of 32x32 tiles (64x64 out)
    const int nt0 = (wave & 1) * 2;

    f32x16 acc00, acc01, acc10, acc11;
#pragma unroll
    for (int i = 0; i < 16; ++i) { acc00[i] = 0.f; acc01[i] = 0.f; acc10[i] = 0.f; acc11[i] = 0.f; }

    // A-staging geometry: 2 threads per row (64 cols each), fp32->bf16, write
    // into A-fragment-linear order: [mt(8)][ks_l(8)][lane(64)][j(8)]
    const int m_st   = tid >> 1;
    const int ch     = (tid & 1) << 6;
    const int mt8_st = (m_st >> 5) * 8;
    const int ml_st  = m_st & 31;

    // ---- GEMM1 phases 0/1: gather x[src] then x[tgt] (K cols 0-127, 128-255)
#pragma unroll
    for (int p = 0; p < 2; ++p) {
        __syncthreads();                       // p0: idx ready; p1: prev sA reads done
        {
            const int row = (p == 0) ? sSrc[m_st] : sTgt[m_st];
            const float4* xr = (const float4*)(x + (size_t)row * 128);
#pragma unroll
            for (int i = 0; i < 16; ++i) {
                const int c = ch + i * 4;
                float4 v = xr[c >> 2];
                bf16x4 bv; bv[0] = (bf16)v.x; bv[1] = (bf16)v.y; bv[2] = (bf16)v.z; bv[3] = (bf16)v.w;
                *((bf16x4*)&sA[((mt8_st + (c >> 4)) * 64 + ml_st + ((c >> 3) & 1) * 32) * 8 + (c & 7)]) = bv;
            }
        }
        __syncthreads();
#pragma unroll
        for (int kl = 0; kl < 8; ++kl) G1_STEP(kl, p * 8 + kl);
    }

    // ---- GEMM1 phase 2: edge_attr (K cols 256-319, coalesced streaming read)
    __syncthreads();
    {
#pragma unroll
        for (int i = 0; i < 8; ++i) {
            const int p4 = tid + i * NTHR;     // 0..4095
            const int m  = p4 >> 4;
            const int c  = (p4 & 15) << 2;     // 0..60
            float4 v = ((const float4*)eattr)[(size_t)(ebase + m) * 16 + (p4 & 15)];
            bf16x4 bv; bv[0] = (bf16)v.x; bv[1] = (bf16)v.y; bv[2] = (bf16)v.z; bv[3] = (bf16)v.w;
            *((bf16x4*)&sA[(((m >> 5) * 8 + (c >> 4)) * 64 + (m & 31) + ((c >> 3) & 1) * 32) * 8 + (c & 7)]) = bv;
        }
    }
    __syncthreads();
#pragma unroll
    for (int kl = 0; kl < 4; ++kl) G1_STEP(kl, 16 + kl);

    // ---- epilogue1: stage W2 into sW region; write relu(h)+b1 into sA (A2 layout)
    __syncthreads();
    {
        const uint4* s4 = (const uint4*)w2f;
        uint4*       d4 = (uint4*)sW;
#pragma unroll
        for (int i = 0; i < 4; ++i) d4[i * NTHR + tid] = s4[i * NTHR + tid];
    }
    {
        const int rowq = (lane >> 5) * 4;
        const int ln   = lane & 31;
        write_h(acc00, mt0,     nt0,     ln, rowq, sA, sB1);
        write_h(acc01, mt0,     nt0 + 1, ln, rowq, sA, sB1);
        write_h(acc10, mt0 + 1, nt0,     ln, rowq, sA, sB1);
        write_h(acc11, mt0 + 1, nt0 + 1, ln, rowq, sA, sB1);
    }
    __syncthreads();

    // ---- GEMM2: out = h @ W2 + b2   (K=128)
#pragma unroll
    for (int i = 0; i < 16; ++i) { acc00[i] = 0.f; acc01[i] = 0.f; acc10[i] = 0.f; acc11[i] = 0.f; }
#pragma unroll
    for (int ks = 0; ks < 8; ++ks) G2_STEP(ks);

    {
        const int rowq = (lane >> 5) * 4;
        const int ln   = lane & 31;
        write_out(acc00, mt0,     nt0,     ln, rowq, ebase, sB2, out);
        write_out(acc01, mt0,     nt0 + 1, ln, rowq, ebase, sB2, out);
        write_out(acc10, mt0 + 1, nt0,     ln, rowq, ebase, sB2, out);
        write_out(acc11, mt0 + 1, nt0 + 1, ln, rowq, ebase, sB2, out);
    }
}

extern "C" void kernel_launch(void* const* d_in, const int* in_sizes, int n_in,
                              void* d_out, int out_size, void* d_ws, size_t ws_size,
                              hipStream_t stream) {
    const float* x   = (const float*)d_in[0];
    const int*   ei  = (const int*)d_in[1];
    const float* ea  = (const float*)d_in[2];
    const float* W1  = (const float*)d_in[3];
    const float* b1  = (const float*)d_in[4];
    const float* W2  = (const float*)d_in[5];
    const float* b2  = (const float*)d_in[6];
    float*       out = (float*)d_out;

    bf16* w1f = (bf16*)d_ws;                          // 40960 bf16 = 81920 B
    bf16* w2f = (bf16*)((char*)d_ws + 81920);         // 16384 bf16 = 32768 B

    prep_weights<<<224, 256, 0, stream>>>(W1, W2, w1f, w2f);

    const size_t shmem = 150528;                      // 147 KB -> 1 block/CU
    edge_mlp<<<N_EDGES / BM, NTHR, shmem, stream>>>(x, ei, ea, w1f, b1, w2f, b2, out);
}